// Round 1
// baseline (151.646 us; speedup 1.0000x reference)
//
#include <hip/hip_runtime.h>
#include <hip/hip_bf16.h>

#define N_Q 4096
#define N_D 8192
#define D_IN 768
#define REP 768
#define NENC 129
#define RDIM 4

typedef __bf16 bf16_t;
typedef __bf16 bf16x4 __attribute__((ext_vector_type(4)));
typedef __bf16 bf16x8 __attribute__((ext_vector_type(8)));
typedef float f32x4 __attribute__((ext_vector_type(4)));

__device__ __forceinline__ void gload_lds16(const void* g, void* l) {
    __builtin_amdgcn_global_load_lds(
        (const __attribute__((address_space(1))) void*)g,
        (__attribute__((address_space(3))) void*)l,
        16, 0, 0);
}

// ---------------- f32 -> bf16 cast (vectorized) ----------------
__global__ void cast_f32_bf16(const float* __restrict__ src, bf16_t* __restrict__ dst, int n4) {
    int i = blockIdx.x * blockDim.x + threadIdx.x;
    if (i < n4) {
        const float4 v = reinterpret_cast<const float4*>(src)[i];
        bf16x4 o;
        o[0] = (bf16_t)v.x; o[1] = (bf16_t)v.y; o[2] = (bf16_t)v.z; o[3] = (bf16_t)v.w;
        reinterpret_cast<bf16x4*>(dst)[i] = o;
    }
}

// ---------------- per-document scalar weight w[j] = pos_enc[argmin|R_j-enc|] . We_w ----------------
__global__ void make_w(const float* __restrict__ R, const float* __restrict__ enc,
                       const float* __restrict__ pos, const float* __restrict__ We_w,
                       float* __restrict__ wout) {
    int j = blockIdx.x * blockDim.x + threadIdx.x;
    if (j < N_D) {
        float r = R[j];
        int best = 0;
        float bd = fabsf(r - enc[0]);
        for (int i = 1; i < NENC; ++i) {
            float d = fabsf(r - enc[i]);
            if (d < bd) { bd = d; best = i; }   // strict < keeps first index, matches jnp.argmin
        }
        float s = 0.f;
        for (int d = 0; d < RDIM; ++d) s += pos[best * RDIM + d] * We_w[d];
        wout[j] = s;
    }
}

// ---------------- BT GEMM: C[M,N] = A[M,K] @ B[N,K]^T, bf16 in, fp32 acc ----------------
// EPI 0: C = acc + bias[col], stored bf16
// EPI 1: partial[nblk][row] = sum_col f(acc) * wcol[col]  (f(a)=a*|a|), deterministic
// 128x128 tile, BK=32, 4 waves (2x2), 4x4 frags of 16x16x32 per wave, global_load_lds width 16.
template <int EPI>
__global__ __launch_bounds__(256)
void gemm_bt(const bf16_t* __restrict__ A, const bf16_t* __restrict__ B,
             const float* __restrict__ bias, bf16_t* __restrict__ Cout,
             const float* __restrict__ wcol, float* __restrict__ partial,
             int M, int N, int K) {
    __shared__ bf16_t As[128 * 32];
    __shared__ bf16_t Bs[128 * 32];
    __shared__ float red[2][128];

    const int tid = threadIdx.x;
    const int wid = tid >> 6;
    const int lane = tid & 63;
    const int wr = wid >> 1, wc = wid & 1;
    const int nblk = blockIdx.x, mblk = blockIdx.y;
    const long mBase = (long)mblk * 128, nBase = (long)nblk * 128;

    // staging geometry: each instr covers 64 rows (16/wave); lane -> (row, 8-elem k-chunk)
    const int sRow = lane >> 2;
    const int sCol = (lane & 3) * 8;

    const bf16_t* gA0 = A + (mBase + wid * 16 + sRow) * (long)K + sCol;
    const bf16_t* gA1 = A + (mBase + 64 + wid * 16 + sRow) * (long)K + sCol;
    const bf16_t* gB0 = B + (nBase + wid * 16 + sRow) * (long)K + sCol;
    const bf16_t* gB1 = B + (nBase + 64 + wid * 16 + sRow) * (long)K + sCol;
    bf16_t* lA0 = &As[(wid * 16) * 32];
    bf16_t* lA1 = &As[(64 + wid * 16) * 32];
    bf16_t* lB0 = &Bs[(wid * 16) * 32];
    bf16_t* lB1 = &Bs[(64 + wid * 16) * 32];

    f32x4 acc[4][4] = {};

    const int lr = lane & 15;
    const int lk = (lane >> 4) * 8;
    const int lq = lane >> 4;

    for (int kt = 0; kt < K; kt += 32) {
        __syncthreads();                       // previous tile's reads done
        gload_lds16(gA0 + kt, lA0);
        gload_lds16(gA1 + kt, lA1);
        gload_lds16(gB0 + kt, lB0);
        gload_lds16(gB1 + kt, lB1);
        __syncthreads();                       // compiler drains vmcnt(0) before barrier
        bf16x8 af[4], bfr[4];
#pragma unroll
        for (int mi = 0; mi < 4; ++mi)
            af[mi] = *reinterpret_cast<const bf16x8*>(&As[(wr * 64 + mi * 16 + lr) * 32 + lk]);
#pragma unroll
        for (int ni = 0; ni < 4; ++ni)
            bfr[ni] = *reinterpret_cast<const bf16x8*>(&Bs[(wc * 64 + ni * 16 + lr) * 32 + lk]);
#pragma unroll
        for (int mi = 0; mi < 4; ++mi)
#pragma unroll
            for (int ni = 0; ni < 4; ++ni)
                acc[mi][ni] = __builtin_amdgcn_mfma_f32_16x16x32_bf16(af[mi], bfr[ni], acc[mi][ni], 0, 0, 0);
    }

    // C/D layout (m89-verified): element j of lane l -> row=(l>>4)*4+j, col=l&15 (within 16x16)
    if constexpr (EPI == 0) {
#pragma unroll
        for (int ni = 0; ni < 4; ++ni) {
            const int col = (int)nBase + wc * 64 + ni * 16 + lr;
            const float bv = bias[col];
#pragma unroll
            for (int mi = 0; mi < 4; ++mi)
#pragma unroll
                for (int j = 0; j < 4; ++j) {
                    const long row = mBase + wr * 64 + mi * 16 + lq * 4 + j;
                    Cout[row * (long)N + col] = (bf16_t)(acc[mi][ni][j] + bv);
                }
        }
    } else {
        float wreg[4];
#pragma unroll
        for (int ni = 0; ni < 4; ++ni) wreg[ni] = wcol[nBase + wc * 64 + ni * 16 + lr];
#pragma unroll
        for (int mi = 0; mi < 4; ++mi)
#pragma unroll
            for (int j = 0; j < 4; ++j) {
                float s = 0.f;
#pragma unroll
                for (int ni = 0; ni < 4; ++ni) {
                    const float a = acc[mi][ni][j];
                    s += a * fabsf(a) * wreg[ni];
                }
                // reduce across the 16 lanes holding this row's 16 columns (lane bits 0..3)
                s += __shfl_xor(s, 1);
                s += __shfl_xor(s, 2);
                s += __shfl_xor(s, 4);
                s += __shfl_xor(s, 8);
                if (lr == 0) red[wc][wr * 64 + mi * 16 + lq * 4 + j] = s;
            }
        __syncthreads();
        if (tid < 128)
            partial[(long)nblk * M + mBase + tid] = red[0][tid] + red[1][tid];
    }
}

// ---------------- final: out[i] = sum_nb partial[nb][i] + We_b ----------------
__global__ void final_reduce(const float* __restrict__ partial, const float* __restrict__ We_b,
                             float* __restrict__ out) {
    int i = blockIdx.x * blockDim.x + threadIdx.x;
    if (i < N_Q) {
        float s = 0.f;
        for (int nb = 0; nb < N_D / 128; ++nb) s += partial[(long)nb * N_Q + i];
        out[i] = s + We_b[0];
    }
}

extern "C" void kernel_launch(void* const* d_in, const int* in_sizes, int n_in,
                              void* d_out, int out_size, void* d_ws, size_t ws_size,
                              hipStream_t stream) {
    const float* X    = (const float*)d_in[0];
    const float* D    = (const float*)d_in[1];
    const float* R    = (const float*)d_in[2];
    const float* Wx_w = (const float*)d_in[3];
    const float* Wx_b = (const float*)d_in[4];
    const float* Wd_w = (const float*)d_in[5];
    const float* Wd_b = (const float*)d_in[6];
    const float* We_w = (const float*)d_in[7];
    const float* We_b = (const float*)d_in[8];
    const float* enc  = (const float*)d_in[9];
    const float* pos  = (const float*)d_in[10];
    float* out = (float*)d_out;

    // workspace carve (~41.2 MB total)
    char* ws = (char*)d_ws;
    bf16_t* Xb   = (bf16_t*)ws; ws += (size_t)N_Q * D_IN * 2;
    bf16_t* Db   = (bf16_t*)ws; ws += (size_t)N_D * D_IN * 2;
    bf16_t* Wxb  = (bf16_t*)ws; ws += (size_t)REP * D_IN * 2;
    bf16_t* Wdb  = (bf16_t*)ws; ws += (size_t)REP * D_IN * 2;
    bf16_t* Xw   = (bf16_t*)ws; ws += (size_t)N_Q * REP * 2;
    bf16_t* Dw   = (bf16_t*)ws; ws += (size_t)N_D * REP * 2;
    float*  wvec = (float*)ws;  ws += (size_t)N_D * 4;
    float*  part = (float*)ws;  ws += (size_t)(N_D / 128) * N_Q * 4;

    cast_f32_bf16<<<(N_Q * D_IN / 4 + 255) / 256, 256, 0, stream>>>(X, Xb, N_Q * D_IN / 4);
    cast_f32_bf16<<<(N_D * D_IN / 4 + 255) / 256, 256, 0, stream>>>(D, Db, N_D * D_IN / 4);
    cast_f32_bf16<<<(REP * D_IN / 4 + 255) / 256, 256, 0, stream>>>(Wx_w, Wxb, REP * D_IN / 4);
    cast_f32_bf16<<<(REP * D_IN / 4 + 255) / 256, 256, 0, stream>>>(Wd_w, Wdb, REP * D_IN / 4);
    make_w<<<(N_D + 255) / 256, 256, 0, stream>>>(R, enc, pos, We_w, wvec);

    // Xw = X @ Wx^T + b  -> bf16
    gemm_bt<0><<<dim3(REP / 128, N_Q / 128), 256, 0, stream>>>(
        Xb, Wxb, Wx_b, Xw, nullptr, nullptr, N_Q, REP, D_IN);
    // Dw = D @ Wd^T + b  -> bf16
    gemm_bt<0><<<dim3(REP / 128, N_D / 128), 256, 0, stream>>>(
        Db, Wdb, Wd_b, Dw, nullptr, nullptr, N_D, REP, D_IN);
    // fused: partial[nb][i] = sum_j f(Xw_i . Dw_j) * w[j]
    gemm_bt<1><<<dim3(N_D / 128, N_Q / 128), 256, 0, stream>>>(
        Xw, Dw, nullptr, nullptr, wvec, part, N_Q, N_D, REP);
    final_reduce<<<(N_Q + 255) / 256, 256, 0, stream>>>(part, We_b, out);
}

// Round 2
// 133.670 us; speedup vs baseline: 1.1345x; 1.1345x over previous
//
#include <hip/hip_runtime.h>
#include <hip/hip_bf16.h>

#define N_Q 4096
#define N_D 8192
#define D_IN 768
#define REP 768
#define NENC 129
#define RDIM 4

typedef __bf16 bf16_t;
typedef __bf16 bf16x4 __attribute__((ext_vector_type(4)));
typedef __bf16 bf16x8 __attribute__((ext_vector_type(8)));
typedef float f32x4 __attribute__((ext_vector_type(4)));

__device__ __forceinline__ void gload_lds16(const void* g, void* l) {
    __builtin_amdgcn_global_load_lds(
        (const __attribute__((address_space(1))) void*)g,
        (__attribute__((address_space(3))) void*)l,
        16, 0, 0);
}

#define BAR() asm volatile("s_barrier" ::: "memory")

// ---------------- f32 -> bf16 cast (vectorized) ----------------
__global__ void cast_f32_bf16(const float* __restrict__ src, bf16_t* __restrict__ dst, int n4) {
    int i = blockIdx.x * blockDim.x + threadIdx.x;
    if (i < n4) {
        const float4 v = reinterpret_cast<const float4*>(src)[i];
        bf16x4 o;
        o[0] = (bf16_t)v.x; o[1] = (bf16_t)v.y; o[2] = (bf16_t)v.z; o[3] = (bf16_t)v.w;
        reinterpret_cast<bf16x4*>(dst)[i] = o;
    }
}

// ---------------- per-document scalar weight ----------------
__global__ void make_w(const float* __restrict__ R, const float* __restrict__ enc,
                       const float* __restrict__ pos, const float* __restrict__ We_w,
                       float* __restrict__ wout) {
    int j = blockIdx.x * blockDim.x + threadIdx.x;
    if (j < N_D) {
        float r = R[j];
        int best = 0;
        float bd = fabsf(r - enc[0]);
        for (int i = 1; i < NENC; ++i) {
            float d = fabsf(r - enc[i]);
            if (d < bd) { bd = d; best = i; }
        }
        float s = 0.f;
        for (int d = 0; d < RDIM; ++d) s += pos[best * RDIM + d] * We_w[d];
        wout[j] = s;
    }
}

// ---------------- projection GEMM (128x128 tile, m97 structure) ----------------
// C = A[M,K] @ B[N,K]^T + bias, stored bf16
__global__ __launch_bounds__(256)
void gemm_bt_bias(const bf16_t* __restrict__ A, const bf16_t* __restrict__ B,
                  const float* __restrict__ bias, bf16_t* __restrict__ Cout,
                  int M, int N, int K) {
    __shared__ bf16_t As[128 * 32];
    __shared__ bf16_t Bs[128 * 32];

    const int tid = threadIdx.x;
    const int wid = tid >> 6;
    const int lane = tid & 63;
    const int wr = wid >> 1, wc = wid & 1;
    const long mBase = (long)blockIdx.y * 128, nBase = (long)blockIdx.x * 128;

    const int sRow = lane >> 2;
    const int sCol = (lane & 3) * 8;

    const bf16_t* gA0 = A + (mBase + wid * 16 + sRow) * (long)K + sCol;
    const bf16_t* gA1 = A + (mBase + 64 + wid * 16 + sRow) * (long)K + sCol;
    const bf16_t* gB0 = B + (nBase + wid * 16 + sRow) * (long)K + sCol;
    const bf16_t* gB1 = B + (nBase + 64 + wid * 16 + sRow) * (long)K + sCol;
    bf16_t* lA0 = &As[(wid * 16) * 32];
    bf16_t* lA1 = &As[(64 + wid * 16) * 32];
    bf16_t* lB0 = &Bs[(wid * 16) * 32];
    bf16_t* lB1 = &Bs[(64 + wid * 16) * 32];

    f32x4 acc[4][4] = {};

    const int lr = lane & 15;
    const int lk = (lane >> 4) * 8;
    const int lq = lane >> 4;

    for (int kt = 0; kt < K; kt += 32) {
        __syncthreads();
        gload_lds16(gA0 + kt, lA0);
        gload_lds16(gA1 + kt, lA1);
        gload_lds16(gB0 + kt, lB0);
        gload_lds16(gB1 + kt, lB1);
        __syncthreads();
        bf16x8 af[4], bfr[4];
#pragma unroll
        for (int mi = 0; mi < 4; ++mi)
            af[mi] = *reinterpret_cast<const bf16x8*>(&As[(wr * 64 + mi * 16 + lr) * 32 + lk]);
#pragma unroll
        for (int ni = 0; ni < 4; ++ni)
            bfr[ni] = *reinterpret_cast<const bf16x8*>(&Bs[(wc * 64 + ni * 16 + lr) * 32 + lk]);
#pragma unroll
        for (int mi = 0; mi < 4; ++mi)
#pragma unroll
            for (int ni = 0; ni < 4; ++ni)
                acc[mi][ni] = __builtin_amdgcn_mfma_f32_16x16x32_bf16(af[mi], bfr[ni], acc[mi][ni], 0, 0, 0);
    }

#pragma unroll
    for (int ni = 0; ni < 4; ++ni) {
        const int col = (int)nBase + wc * 64 + ni * 16 + lr;
        const float bv = bias[col];
#pragma unroll
        for (int mi = 0; mi < 4; ++mi)
#pragma unroll
            for (int j = 0; j < 4; ++j) {
                const long row = mBase + wr * 64 + mi * 16 + lq * 4 + j;
                Cout[row * (long)N + col] = (bf16_t)(acc[mi][ni][j] + bv);
            }
    }
}

// ---------------- fused 256x256 deep-pipelined GEMM ----------------
// partial[nblk][row] = sum_col f(Xw_row . Dw_col) * w[col],  f(a)=a*|a|
// 512 thr (8 waves 2x4), BK=32, 4-buffer LDS ring, counted vmcnt(8), swizzled LDS.
// LDS layout per 16KB block: logical (m in 0..255, kk in 0..31) at linear q = m*64+kk*2,
// physical p = q ^ (((q>>7)&7)<<4)  (XOR involution within 128B line; verified conflict-free).
__global__ __launch_bounds__(512, 2)
void gemm_fused256(const bf16_t* __restrict__ A, const bf16_t* __restrict__ B,
                   const float* __restrict__ wcol, float* __restrict__ partial) {
    constexpr int K = REP;
    constexpr int KT = K / 32;   // 24 K-tiles
    __shared__ bf16_t As[4][128 * 64];
    __shared__ bf16_t Bs[4][128 * 64];
    __shared__ float red[4][256];

    const int t = threadIdx.x;
    const int lane = t & 63;
    const int wid = t >> 6;
    const int lr = lane & 15;
    const int lq = lane >> 4;
    const int wr = wid >> 2;      // 0..1 (m half)
    const int wc = wid & 3;       // 0..3 (n quarter)
    const long mBase = (long)blockIdx.y * 256;
    const long nBase = (long)blockIdx.x * 256;

    // staging: thread t owns LDS bytes p0 = t*16 (g=0) and p0+8192 (g=1) of each 16KB block.
    // source = inverse-swizzled logical element (same XOR involution).
    const int p0 = t * 16;
    const int q0 = p0 ^ (((p0 >> 7) & 7) << 4);
    const int sm = q0 >> 6;            // 0..127
    const int sk = (q0 & 63) >> 1;     // 0,8,16,24
    const bf16_t* gA = A + (mBase + sm) * (long)K + sk;
    const bf16_t* gB = B + (nBase + sm) * (long)K + sk;
    const int dOff = wid * 1024;       // wave-uniform LDS dest base

#define STAGE_A(kt) do { const int _k = (kt); const bf16_t* _s = gA + _k * 32; \
        char* _d = (char*)As[_k & 3] + dOff; \
        gload_lds16(_s, _d); \
        gload_lds16(_s + 128 * (long)K, _d + 8192); } while (0)
#define STAGE_B(kt) do { const int _k = (kt); const bf16_t* _s = gB + _k * 32; \
        char* _d = (char*)Bs[_k & 3] + dOff; \
        gload_lds16(_s, _d); \
        gload_lds16(_s + 128 * (long)K, _d + 8192); } while (0)

    // ds_read bases (swizzled); frag-to-frag offset is a constant 1024B.
    const int am = wr * 128 + lr;
    const int apA = (am * 64 + lq * 16) ^ (((am >> 1) & 7) << 4);
    const int bn = wc * 64 + lr;
    const int apB = (bn * 64 + lq * 16) ^ (((bn >> 1) & 7) << 4);

    f32x4 acc[8][4] = {};

    // prologue: tiles 0,1,2 in flight; drain tile 0 (keep 8 = tiles 1,2 outstanding)
    STAGE_A(0); STAGE_B(0);
    STAGE_A(1); STAGE_B(1);
    STAGE_A(2); STAGE_B(2);
    asm volatile("s_waitcnt vmcnt(8)" ::: "memory");
    BAR();

#pragma unroll 4
    for (int k = 0; k < KT; ++k) {
        const char* Ab = (const char*)As[k & 3];
        const char* Bb = (const char*)Bs[k & 3];
        const int pre = (k + 3 < KT) ? k + 3 : KT - 1;   // clamp keeps vmcnt counts fixed

        // ---- phase 0: m-frags 0..3 ----
        bf16x8 a[4], b[4];
#pragma unroll
        for (int i = 0; i < 4; ++i) {
            a[i] = *reinterpret_cast<const bf16x8*>(Ab + apA + i * 1024);
            b[i] = *reinterpret_cast<const bf16x8*>(Bb + apB + i * 1024);
        }
        STAGE_A(pre);
        BAR();
        __builtin_amdgcn_s_setprio(1);
#pragma unroll
        for (int mi = 0; mi < 4; ++mi)
#pragma unroll
            for (int ni = 0; ni < 4; ++ni)
                acc[mi][ni] = __builtin_amdgcn_mfma_f32_16x16x32_bf16(a[mi], b[ni], acc[mi][ni], 0, 0, 0);
        __builtin_amdgcn_s_setprio(0);
        BAR();

        // ---- phase 1: m-frags 4..7 (reuse b) ----
#pragma unroll
        for (int i = 0; i < 4; ++i)
            a[i] = *reinterpret_cast<const bf16x8*>(Ab + apA + 4096 + i * 1024);
        STAGE_B(pre);
        BAR();
        __builtin_amdgcn_s_setprio(1);
#pragma unroll
        for (int mi = 0; mi < 4; ++mi)
#pragma unroll
            for (int ni = 0; ni < 4; ++ni)
                acc[mi + 4][ni] = __builtin_amdgcn_mfma_f32_16x16x32_bf16(a[mi], b[ni], acc[mi + 4][ni], 0, 0, 0);
        __builtin_amdgcn_s_setprio(0);
        asm volatile("s_waitcnt vmcnt(8)" ::: "memory");  // tile k+1 resident; 4 stages in flight
        BAR();
    }
#undef STAGE_A
#undef STAGE_B

    // epilogue: f(a)*w, reduce over n
    float wreg[4];
#pragma unroll
    for (int ni = 0; ni < 4; ++ni) wreg[ni] = wcol[nBase + wc * 64 + ni * 16 + lr];

#pragma unroll
    for (int mi = 0; mi < 8; ++mi)
#pragma unroll
        for (int j = 0; j < 4; ++j) {
            float s = 0.f;
#pragma unroll
            for (int ni = 0; ni < 4; ++ni) {
                const float av = acc[mi][ni][j];
                s += av * fabsf(av) * wreg[ni];
            }
            s += __shfl_xor(s, 1);
            s += __shfl_xor(s, 2);
            s += __shfl_xor(s, 4);
            s += __shfl_xor(s, 8);
            if (lr == 0) red[wc][wr * 128 + mi * 16 + lq * 4 + j] = s;
        }
    __syncthreads();
    if (t < 256)
        partial[(long)blockIdx.x * N_Q + mBase + t]
            = red[0][t] + red[1][t] + red[2][t] + red[3][t];
}

// ---------------- final: out[i] = sum_nb partial[nb][i] + We_b ----------------
__global__ void final_reduce(const float* __restrict__ partial, const float* __restrict__ We_b,
                             float* __restrict__ out) {
    int i = blockIdx.x * blockDim.x + threadIdx.x;
    if (i < N_Q) {
        float s = 0.f;
        for (int nb = 0; nb < N_D / 256; ++nb) s += partial[(long)nb * N_Q + i];
        out[i] = s + We_b[0];
    }
}

extern "C" void kernel_launch(void* const* d_in, const int* in_sizes, int n_in,
                              void* d_out, int out_size, void* d_ws, size_t ws_size,
                              hipStream_t stream) {
    const float* X    = (const float*)d_in[0];
    const float* D    = (const float*)d_in[1];
    const float* R    = (const float*)d_in[2];
    const float* Wx_w = (const float*)d_in[3];
    const float* Wx_b = (const float*)d_in[4];
    const float* Wd_w = (const float*)d_in[5];
    const float* Wd_b = (const float*)d_in[6];
    const float* We_w = (const float*)d_in[7];
    const float* We_b = (const float*)d_in[8];
    const float* enc  = (const float*)d_in[9];
    const float* pos  = (const float*)d_in[10];
    float* out = (float*)d_out;

    char* ws = (char*)d_ws;
    bf16_t* Xb   = (bf16_t*)ws; ws += (size_t)N_Q * D_IN * 2;
    bf16_t* Db   = (bf16_t*)ws; ws += (size_t)N_D * D_IN * 2;
    bf16_t* Wxb  = (bf16_t*)ws; ws += (size_t)REP * D_IN * 2;
    bf16_t* Wdb  = (bf16_t*)ws; ws += (size_t)REP * D_IN * 2;
    bf16_t* Xw   = (bf16_t*)ws; ws += (size_t)N_Q * REP * 2;
    bf16_t* Dw   = (bf16_t*)ws; ws += (size_t)N_D * REP * 2;
    float*  wvec = (float*)ws;  ws += (size_t)N_D * 4;
    float*  part = (float*)ws;  ws += (size_t)(N_D / 256) * N_Q * 4;

    cast_f32_bf16<<<(N_Q * D_IN / 4 + 255) / 256, 256, 0, stream>>>(X, Xb, N_Q * D_IN / 4);
    cast_f32_bf16<<<(N_D * D_IN / 4 + 255) / 256, 256, 0, stream>>>(D, Db, N_D * D_IN / 4);
    cast_f32_bf16<<<(REP * D_IN / 4 + 255) / 256, 256, 0, stream>>>(Wx_w, Wxb, REP * D_IN / 4);
    cast_f32_bf16<<<(REP * D_IN / 4 + 255) / 256, 256, 0, stream>>>(Wd_w, Wdb, REP * D_IN / 4);
    make_w<<<(N_D + 255) / 256, 256, 0, stream>>>(R, enc, pos, We_w, wvec);

    gemm_bt_bias<<<dim3(REP / 128, N_Q / 128), 256, 0, stream>>>(
        Xb, Wxb, Wx_b, Xw, N_Q, REP, D_IN);
    gemm_bt_bias<<<dim3(REP / 128, N_D / 128), 256, 0, stream>>>(
        Db, Wdb, Wd_b, Dw, N_D, REP, D_IN);

    gemm_fused256<<<dim3(N_D / 256, N_Q / 256), 512, 0, stream>>>(Xw, Dw, wvec, part);

    final_reduce<<<(N_Q + 255) / 256, 256, 0, stream>>>(part, We_b, out);
}

// Round 3
// 127.071 us; speedup vs baseline: 1.1934x; 1.0519x over previous
//
#include <hip/hip_runtime.h>
#include <hip/hip_bf16.h>

#define N_Q 4096
#define N_D 8192
#define D_IN 768
#define REP 768
#define NENC 129
#define RDIM 4

typedef __bf16 bf16_t;
typedef __bf16 bf16x4 __attribute__((ext_vector_type(4)));
typedef __bf16 bf16x8 __attribute__((ext_vector_type(8)));
typedef float f32x4 __attribute__((ext_vector_type(4)));
typedef float f32x16 __attribute__((ext_vector_type(16)));

__device__ __forceinline__ void gload_lds16(const void* g, void* l) {
    __builtin_amdgcn_global_load_lds(
        (const __attribute__((address_space(1))) void*)g,
        (__attribute__((address_space(3))) void*)l,
        16, 0, 0);
}

#define BAR() asm volatile("s_barrier" ::: "memory")

// ---------------- prep: all f32->bf16 casts + per-doc weight, ONE launch ----------------
__device__ __forceinline__ void cast4(const float* __restrict__ s, bf16_t* __restrict__ d, int i) {
    const float4 v = reinterpret_cast<const float4*>(s)[i];
    bf16x4 o;
    o[0] = (bf16_t)v.x; o[1] = (bf16_t)v.y; o[2] = (bf16_t)v.z; o[3] = (bf16_t)v.w;
    reinterpret_cast<bf16x4*>(d)[i] = o;
}

__global__ void prep(const float* __restrict__ X, const float* __restrict__ D,
                     const float* __restrict__ Wx, const float* __restrict__ Wd,
                     bf16_t* __restrict__ Xb, bf16_t* __restrict__ Db,
                     bf16_t* __restrict__ Wxb, bf16_t* __restrict__ Wdb,
                     const float* __restrict__ R, const float* __restrict__ enc,
                     const float* __restrict__ pos, const float* __restrict__ We_w,
                     float* __restrict__ wout) {
    constexpr int C_X  = N_Q * D_IN / 4;
    constexpr int C_D  = C_X + N_D * D_IN / 4;
    constexpr int C_WX = C_D + REP * D_IN / 4;
    constexpr int C_WD = C_WX + REP * D_IN / 4;
    const int i = blockIdx.x * blockDim.x + threadIdx.x;
    if (i < C_X)       cast4(X,  Xb,  i);
    else if (i < C_D)  cast4(D,  Db,  i - C_X);
    else if (i < C_WX) cast4(Wx, Wxb, i - C_D);
    else if (i < C_WD) cast4(Wd, Wdb, i - C_WX);
    else {
        const int j = i - C_WD;
        if (j < N_D) {
            const float r = R[j];
            int best = 0;
            float bd = fabsf(r - enc[0]);
            for (int e = 1; e < NENC; ++e) {
                const float d = fabsf(r - enc[e]);
                if (d < bd) { bd = d; best = e; }   // strict <, matches jnp.argmin
            }
            float s = 0.f;
            for (int d = 0; d < RDIM; ++d) s += pos[best * RDIM + d] * We_w[d];
            wout[j] = s;
        }
    }
}

// ---------------- merged projection GEMM (Xw and Dw in one launch) ----------------
// C = A[M,768] @ W[768,768]^T + bias, stored bf16. 128x128 tile, m97 structure.
__global__ __launch_bounds__(256)
void proj_gemm(const bf16_t* __restrict__ Xb, const bf16_t* __restrict__ Db,
               const bf16_t* __restrict__ Wxb, const bf16_t* __restrict__ Wdb,
               const float* __restrict__ bx, const float* __restrict__ bd,
               bf16_t* __restrict__ Xw, bf16_t* __restrict__ Dw) {
    constexpr int K = D_IN, N = REP;
    __shared__ bf16_t As[128 * 32];
    __shared__ bf16_t Bs[128 * 32];

    const bool isX = blockIdx.y < (N_Q / 128);
    const bf16_t* A  = isX ? Xb : Db;
    const bf16_t* Bw = isX ? Wxb : Wdb;
    const float* bias = isX ? bx : bd;
    bf16_t* C = isX ? Xw : Dw;
    const long mBase = (long)(isX ? blockIdx.y : blockIdx.y - N_Q / 128) * 128;
    const long nBase = (long)blockIdx.x * 128;

    const int tid = threadIdx.x;
    const int wid = tid >> 6;
    const int lane = tid & 63;
    const int wr = wid >> 1, wc = wid & 1;
    const int sRow = lane >> 2;
    const int sCol = (lane & 3) * 8;

    const bf16_t* gA0 = A  + (mBase + wid * 16 + sRow) * (long)K + sCol;
    const bf16_t* gA1 = A  + (mBase + 64 + wid * 16 + sRow) * (long)K + sCol;
    const bf16_t* gB0 = Bw + (nBase + wid * 16 + sRow) * (long)K + sCol;
    const bf16_t* gB1 = Bw + (nBase + 64 + wid * 16 + sRow) * (long)K + sCol;
    bf16_t* lA0 = &As[(wid * 16) * 32];
    bf16_t* lA1 = &As[(64 + wid * 16) * 32];
    bf16_t* lB0 = &Bs[(wid * 16) * 32];
    bf16_t* lB1 = &Bs[(64 + wid * 16) * 32];

    f32x4 acc[4][4] = {};
    const int lr = lane & 15;
    const int lk = (lane >> 4) * 8;
    const int lq = lane >> 4;

    for (int kt = 0; kt < K; kt += 32) {
        __syncthreads();
        gload_lds16(gA0 + kt, lA0);
        gload_lds16(gA1 + kt, lA1);
        gload_lds16(gB0 + kt, lB0);
        gload_lds16(gB1 + kt, lB1);
        __syncthreads();
        bf16x8 af[4], bfr[4];
#pragma unroll
        for (int mi = 0; mi < 4; ++mi)
            af[mi] = *reinterpret_cast<const bf16x8*>(&As[(wr * 64 + mi * 16 + lr) * 32 + lk]);
#pragma unroll
        for (int ni = 0; ni < 4; ++ni)
            bfr[ni] = *reinterpret_cast<const bf16x8*>(&Bs[(wc * 64 + ni * 16 + lr) * 32 + lk]);
#pragma unroll
        for (int mi = 0; mi < 4; ++mi)
#pragma unroll
            for (int ni = 0; ni < 4; ++ni)
                acc[mi][ni] = __builtin_amdgcn_mfma_f32_16x16x32_bf16(af[mi], bfr[ni], acc[mi][ni], 0, 0, 0);
    }

#pragma unroll
    for (int ni = 0; ni < 4; ++ni) {
        const int col = (int)nBase + wc * 64 + ni * 16 + lr;
        const float bv = bias[col];
#pragma unroll
        for (int mi = 0; mi < 4; ++mi)
#pragma unroll
            for (int j = 0; j < 4; ++j) {
                const long row = mBase + wr * 64 + mi * 16 + lq * 4 + j;
                C[row * (long)N + col] = (bf16_t)(acc[mi][ni][j] + bv);
            }
    }
}

// ---------------- fused 256x256 GEMM, 32x32x16 MFMA, reg-pipelined phases ----------------
// partial[nblk][row] = sum_col f(Xw_row . Dw_col) * w[col],  f(a)=a*|a|
// 8 waves (2M x 4N), per-wave 128x64 = 4x2 frags of 32x32. BK=32 (2 kslices of 16).
// 4-buffer LDS ring; ONE barrier + ONE counted vmcnt(4) per K-tile; next-phase ds_reads
// issued before current MFMA cluster (reg double-buffer) so LDS drains under MFMA.
// LDS byte layout per 16KB block: q = row*64 + kk*2, p = q ^ (((q>>7)&7)<<4).
__global__ __launch_bounds__(512, 2)
void gemm_fused256(const bf16_t* __restrict__ A, const bf16_t* __restrict__ B,
                   const float* __restrict__ wcol, float* __restrict__ partial) {
    constexpr int K = REP;
    constexpr int KT = K / 32;   // 24 K-tiles
    __shared__ bf16_t As[4][256 * 32];
    __shared__ bf16_t Bs[4][256 * 32];
    __shared__ float red[4][256];

    const int t = threadIdx.x;
    const int lane = t & 63;
    const int wid = t >> 6;
    const int l31 = lane & 31;
    const int hi = lane >> 5;
    const int wr = wid >> 2;      // 0..1 (m half, 128 rows)
    const int wc = wid & 3;       // 0..3 (n quarter, 64 cols)
    const long mBase = (long)blockIdx.y * 256;
    const long nBase = (long)blockIdx.x * 256;

    // staging: thread t owns LDS bytes p0=t*16 (rows 0..127) and p0+8192 (rows 128..255)
    // of each 16KB block; global source = inverse-swizzled logical element.
    const int p0 = t * 16;
    const int q0 = p0 ^ (((p0 >> 7) & 7) << 4);
    const int sm = q0 >> 6;
    const int sk = (q0 & 63) >> 1;
    const bf16_t* gA = A + (mBase + sm) * (long)K + sk;
    const bf16_t* gB = B + (nBase + sm) * (long)K + sk;
    const int dOff = wid * 1024;

#define STAGE_A(kt) do { const int _k = (kt); const bf16_t* _s = gA + _k * 32; \
        char* _d = (char*)As[_k & 3] + dOff; \
        gload_lds16(_s, _d); \
        gload_lds16(_s + 128 * (long)K, _d + 8192); } while (0)
#define STAGE_B(kt) do { const int _k = (kt); const bf16_t* _s = gB + _k * 32; \
        char* _d = (char*)Bs[_k & 3] + dOff; \
        gload_lds16(_s, _d); \
        gload_lds16(_s + 128 * (long)K, _d + 8192); } while (0)

    // ds_read bases: A-frag row = wr*128 + mi*32 + l31, kk = s*16 + hi*8.
    // swizzle key = (row>>1)&7 is invariant to mi (+32 rows) and wr/wc; kslice = XOR 32.
    const int rA = wr * 128 + l31;
    const int pA0 = ((rA * 64 + hi * 16) ^ (((rA >> 1) & 7) << 4));
    const int pA1 = pA0 ^ 32;
    const int rB = wc * 64 + l31;
    const int pB0 = ((rB * 64 + hi * 16) ^ (((rB >> 1) & 7) << 4));
    const int pB1 = pB0 ^ 32;

#define LDK(AA, BB, bufc, sx) do { \
        const char* _a = (const char*)As + (bufc) * 16384; \
        const char* _b = (const char*)Bs + (bufc) * 16384; \
        const int _pa = (sx) ? pA1 : pA0; \
        const int _pb = (sx) ? pB1 : pB0; \
        AA[0] = *reinterpret_cast<const bf16x8*>(_a + _pa); \
        AA[1] = *reinterpret_cast<const bf16x8*>(_a + _pa + 2048); \
        AA[2] = *reinterpret_cast<const bf16x8*>(_a + _pa + 4096); \
        AA[3] = *reinterpret_cast<const bf16x8*>(_a + _pa + 6144); \
        BB[0] = *reinterpret_cast<const bf16x8*>(_b + _pb); \
        BB[1] = *reinterpret_cast<const bf16x8*>(_b + _pb + 2048); \
    } while (0)

    f32x16 acc[4][2] = {};
    bf16x8 cA[4], cB[2], nA[4], nB[2];

    // prologue: tiles 0,1,2 in flight (12 loads); drain tiles 0,1 (keep tile 2's 4)
    STAGE_A(0); STAGE_B(0);
    STAGE_A(1); STAGE_B(1);
    STAGE_A(2); STAGE_B(2);
    asm volatile("s_waitcnt vmcnt(4)" ::: "memory");
    BAR();
    LDK(cA, cB, 0, 0);

#pragma unroll 4
    for (int k = 0; k < KT; ++k) {
        const int pre = (k + 3 < KT) ? k + 3 : KT - 1;   // idempotent re-stage keeps counts uniform

        // phase A: prefetch (k, s1); stage A(pre); MFMA (k, s0)
        STAGE_A(pre);
        LDK(nA, nB, k & 3, 1);
        __builtin_amdgcn_s_setprio(1);
#pragma unroll
        for (int mi = 0; mi < 4; ++mi)
#pragma unroll
            for (int ni = 0; ni < 2; ++ni)
                acc[mi][ni] = __builtin_amdgcn_mfma_f32_32x32x16_bf16(cA[mi], cB[ni], acc[mi][ni], 0, 0, 0);
        __builtin_amdgcn_s_setprio(0);

        // phase B: prefetch (k+1, s0); stage B(pre); MFMA (k, s1)
        STAGE_B(pre);
        if (k + 1 < KT) LDK(cA, cB, (k + 1) & 3, 0);
        __builtin_amdgcn_s_setprio(1);
#pragma unroll
        for (int mi = 0; mi < 4; ++mi)
#pragma unroll
            for (int ni = 0; ni < 2; ++ni)
                acc[mi][ni] = __builtin_amdgcn_mfma_f32_32x32x16_bf16(nA[mi], nB[ni], acc[mi][ni], 0, 0, 0);
        __builtin_amdgcn_s_setprio(0);

        asm volatile("s_waitcnt vmcnt(4)" ::: "memory");  // tiles <= k+2 resident
        BAR();
    }
#undef STAGE_A
#undef STAGE_B
#undef LDK

    // epilogue: C/D layout (m74/m101): col = lane&31, row = (r&3) + 8*(r>>2) + 4*hi
    float wv[2];
    wv[0] = wcol[nBase + wc * 64 + l31];
    wv[1] = wcol[nBase + wc * 64 + 32 + l31];

#pragma unroll
    for (int mi = 0; mi < 4; ++mi)
#pragma unroll
        for (int r = 0; r < 16; ++r) {
            const float a0 = acc[mi][0][r];
            const float a1 = acc[mi][1][r];
            float s = a0 * fabsf(a0) * wv[0] + a1 * fabsf(a1) * wv[1];
            s += __shfl_xor(s, 1);
            s += __shfl_xor(s, 2);
            s += __shfl_xor(s, 4);
            s += __shfl_xor(s, 8);
            s += __shfl_xor(s, 16);
            if (l31 == 0)
                red[wc][wr * 128 + mi * 32 + (r & 3) + 8 * (r >> 2) + 4 * hi] = s;
        }
    __syncthreads();
    if (t < 256)
        partial[(long)blockIdx.x * N_Q + mBase + t]
            = red[0][t] + red[1][t] + red[2][t] + red[3][t];
}

// ---------------- final: out[i] = sum_nb partial[nb][i] + We_b ----------------
__global__ void final_reduce(const float* __restrict__ partial, const float* __restrict__ We_b,
                             float* __restrict__ out) {
    int i = blockIdx.x * blockDim.x + threadIdx.x;
    if (i < N_Q) {
        float s = 0.f;
        for (int nb = 0; nb < N_D / 256; ++nb) s += partial[(long)nb * N_Q + i];
        out[i] = s + We_b[0];
    }
}

extern "C" void kernel_launch(void* const* d_in, const int* in_sizes, int n_in,
                              void* d_out, int out_size, void* d_ws, size_t ws_size,
                              hipStream_t stream) {
    const float* X    = (const float*)d_in[0];
    const float* D    = (const float*)d_in[1];
    const float* R    = (const float*)d_in[2];
    const float* Wx_w = (const float*)d_in[3];
    const float* Wx_b = (const float*)d_in[4];
    const float* Wd_w = (const float*)d_in[5];
    const float* Wd_b = (const float*)d_in[6];
    const float* We_w = (const float*)d_in[7];
    const float* We_b = (const float*)d_in[8];
    const float* enc  = (const float*)d_in[9];
    const float* pos  = (const float*)d_in[10];
    float* out = (float*)d_out;

    char* ws = (char*)d_ws;
    bf16_t* Xb   = (bf16_t*)ws; ws += (size_t)N_Q * D_IN * 2;
    bf16_t* Db   = (bf16_t*)ws; ws += (size_t)N_D * D_IN * 2;
    bf16_t* Wxb  = (bf16_t*)ws; ws += (size_t)REP * D_IN * 2;
    bf16_t* Wdb  = (bf16_t*)ws; ws += (size_t)REP * D_IN * 2;
    bf16_t* Xw   = (bf16_t*)ws; ws += (size_t)N_Q * REP * 2;
    bf16_t* Dw   = (bf16_t*)ws; ws += (size_t)N_D * REP * 2;
    float*  wvec = (float*)ws;  ws += (size_t)N_D * 4;
    float*  part = (float*)ws;  ws += (size_t)(N_D / 256) * N_Q * 4;

    constexpr int PREP_N = (N_Q * D_IN + N_D * D_IN + 2 * REP * D_IN) / 4 + N_D;
    prep<<<(PREP_N + 255) / 256, 256, 0, stream>>>(
        X, D, Wx_w, Wd_w, Xb, Db, Wxb, Wdb, R, enc, pos, We_w, wvec);

    proj_gemm<<<dim3(REP / 128, (N_Q + N_D) / 128), 256, 0, stream>>>(
        Xb, Db, Wxb, Wdb, Wx_b, Wd_b, Xw, Dw);

    gemm_fused256<<<dim3(N_D / 256, N_Q / 256), 512, 0, stream>>>(Xw, Dw, wvec, part);

    final_reduce<<<(N_Q + 255) / 256, 256, 0, stream>>>(part, We_b, out);
}

// Round 4
// 107.432 us; speedup vs baseline: 1.4116x; 1.1828x over previous
//
#include <hip/hip_runtime.h>
#include <hip/hip_bf16.h>

#define N_Q 4096
#define N_D 8192
#define D_IN 768
#define REP 768
#define NENC 129
#define RDIM 4

typedef __bf16 bf16_t;
typedef __bf16 bf16x4 __attribute__((ext_vector_type(4)));
typedef __bf16 bf16x8 __attribute__((ext_vector_type(8)));
typedef float f32x4 __attribute__((ext_vector_type(4)));

__device__ __forceinline__ void gload_lds16(const void* g, void* l) {
    __builtin_amdgcn_global_load_lds(
        (const __attribute__((address_space(1))) void*)g,
        (__attribute__((address_space(3))) void*)l,
        16, 0, 0);
}

__device__ __forceinline__ unsigned ldsAddr(const void* p) {
    return (unsigned)(unsigned long long)(const __attribute__((address_space(3))) char*)p;
}

template <int OFF>
__device__ __forceinline__ bf16x8 ds_read_b128_off(unsigned addr) {
    bf16x8 r;
    asm volatile("ds_read_b128 %0, %1 offset:%2" : "=v"(r) : "v"(addr), "i"(OFF));
    return r;
}

#define BAR() asm volatile("s_barrier" ::: "memory")

// ---------------- prep: all f32->bf16 casts + per-doc weight, ONE launch ----------------
__device__ __forceinline__ void cast4(const float* __restrict__ s, bf16_t* __restrict__ d, int i) {
    const float4 v = reinterpret_cast<const float4*>(s)[i];
    bf16x4 o;
    o[0] = (bf16_t)v.x; o[1] = (bf16_t)v.y; o[2] = (bf16_t)v.z; o[3] = (bf16_t)v.w;
    reinterpret_cast<bf16x4*>(d)[i] = o;
}

__global__ void prep(const float* __restrict__ X, const float* __restrict__ D,
                     const float* __restrict__ Wx, const float* __restrict__ Wd,
                     bf16_t* __restrict__ Xb, bf16_t* __restrict__ Db,
                     bf16_t* __restrict__ Wxb, bf16_t* __restrict__ Wdb,
                     const float* __restrict__ R, const float* __restrict__ enc,
                     const float* __restrict__ pos, const float* __restrict__ We_w,
                     float* __restrict__ wout) {
    constexpr int C_X  = N_Q * D_IN / 4;
    constexpr int C_D  = C_X + N_D * D_IN / 4;
    constexpr int C_WX = C_D + REP * D_IN / 4;
    constexpr int C_WD = C_WX + REP * D_IN / 4;
    const int i = blockIdx.x * blockDim.x + threadIdx.x;
    if (i < C_X)       cast4(X,  Xb,  i);
    else if (i < C_D)  cast4(D,  Db,  i - C_X);
    else if (i < C_WX) cast4(Wx, Wxb, i - C_D);
    else if (i < C_WD) cast4(Wd, Wdb, i - C_WX);
    else {
        const int j = i - C_WD;
        if (j < N_D) {
            const float r = R[j];
            int best = 0;
            float bd = fabsf(r - enc[0]);
            for (int e = 1; e < NENC; ++e) {
                const float d = fabsf(r - enc[e]);
                if (d < bd) { bd = d; best = e; }   // strict <, matches jnp.argmin
            }
            float s = 0.f;
            for (int d = 0; d < RDIM; ++d) s += pos[best * RDIM + d] * We_w[d];
            wout[j] = s;
        }
    }
}

// ---------------- merged projection GEMM (Xw and Dw in one launch) ----------------
__global__ __launch_bounds__(256)
void proj_gemm(const bf16_t* __restrict__ Xb, const bf16_t* __restrict__ Db,
               const bf16_t* __restrict__ Wxb, const bf16_t* __restrict__ Wdb,
               const float* __restrict__ bx, const float* __restrict__ bd,
               bf16_t* __restrict__ Xw, bf16_t* __restrict__ Dw) {
    constexpr int K = D_IN, N = REP;
    __shared__ bf16_t As[128 * 32];
    __shared__ bf16_t Bs[128 * 32];

    const bool isX = blockIdx.y < (N_Q / 128);
    const bf16_t* A  = isX ? Xb : Db;
    const bf16_t* Bw = isX ? Wxb : Wdb;
    const float* bias = isX ? bx : bd;
    bf16_t* C = isX ? Xw : Dw;
    const long mBase = (long)(isX ? blockIdx.y : blockIdx.y - N_Q / 128) * 128;
    const long nBase = (long)blockIdx.x * 128;

    const int tid = threadIdx.x;
    const int wid = tid >> 6;
    const int lane = tid & 63;
    const int wr = wid >> 1, wc = wid & 1;
    const int sRow = lane >> 2;
    const int sCol = (lane & 3) * 8;

    const bf16_t* gA0 = A  + (mBase + wid * 16 + sRow) * (long)K + sCol;
    const bf16_t* gA1 = A  + (mBase + 64 + wid * 16 + sRow) * (long)K + sCol;
    const bf16_t* gB0 = Bw + (nBase + wid * 16 + sRow) * (long)K + sCol;
    const bf16_t* gB1 = Bw + (nBase + 64 + wid * 16 + sRow) * (long)K + sCol;
    bf16_t* lA0 = &As[(wid * 16) * 32];
    bf16_t* lA1 = &As[(64 + wid * 16) * 32];
    bf16_t* lB0 = &Bs[(wid * 16) * 32];
    bf16_t* lB1 = &Bs[(64 + wid * 16) * 32];

    f32x4 acc[4][4] = {};
    const int lr = lane & 15;
    const int lk = (lane >> 4) * 8;
    const int lq = lane >> 4;

    for (int kt = 0; kt < K; kt += 32) {
        __syncthreads();
        gload_lds16(gA0 + kt, lA0);
        gload_lds16(gA1 + kt, lA1);
        gload_lds16(gB0 + kt, lB0);
        gload_lds16(gB1 + kt, lB1);
        __syncthreads();
        bf16x8 af[4], bfr[4];
#pragma unroll
        for (int mi = 0; mi < 4; ++mi)
            af[mi] = *reinterpret_cast<const bf16x8*>(&As[(wr * 64 + mi * 16 + lr) * 32 + lk]);
#pragma unroll
        for (int ni = 0; ni < 4; ++ni)
            bfr[ni] = *reinterpret_cast<const bf16x8*>(&Bs[(wc * 64 + ni * 16 + lr) * 32 + lk]);
#pragma unroll
        for (int mi = 0; mi < 4; ++mi)
#pragma unroll
            for (int ni = 0; ni < 4; ++ni)
                acc[mi][ni] = __builtin_amdgcn_mfma_f32_16x16x32_bf16(af[mi], bfr[ni], acc[mi][ni], 0, 0, 0);
    }

#pragma unroll
    for (int ni = 0; ni < 4; ++ni) {
        const int col = (int)nBase + wc * 64 + ni * 16 + lr;
        const float bv = bias[col];
#pragma unroll
        for (int mi = 0; mi < 4; ++mi)
#pragma unroll
            for (int j = 0; j < 4; ++j) {
                const long row = mBase + wr * 64 + mi * 16 + lq * 4 + j;
                C[row * (long)N + col] = (bf16_t)(acc[mi][ni][j] + bv);
            }
    }
}

// ---------------- fused 256x256 GEMM, m201-discipline phases ----------------
// partial[nblk][row] = sum_col f(Xw_row . Dw_col) * w[col],  f(a)=a*|a|
// 8 waves (2M x 4N), per-wave 128x64 of 16x16x32 frags. Ring of 4 BK=32 tiles.
// Per K-tile, 2 phases: {asm ds_read (8|4) -> STAGE -> barrier -> lgkmcnt(0) ->
// sched_barrier -> setprio(1) 16 MFMA setprio(0) -> sched_barrier -> barrier};
// single counted vmcnt(8) per tile (2-tile lookahead resident, 2 tiles in flight).
// LDS tile layout: q = row*64 + kk*2, p = q ^ (((q>>7)&7)<<4)  (verified 0-conflict, r2).
__global__ __launch_bounds__(512, 2)
void gemm_fused256(const bf16_t* __restrict__ A, const bf16_t* __restrict__ B,
                   const float* __restrict__ wcol, float* __restrict__ partial) {
    constexpr int KT = REP / 32;   // 24 K-tiles
    __shared__ bf16_t As[4][256 * 32];
    __shared__ bf16_t Bs[4][256 * 32];
    __shared__ float red[4][256];

    const int t = threadIdx.x;
    const int lane = t & 63;
    const int wid = t >> 6;
    const int lr = lane & 15;
    const int lq = lane >> 4;
    const int wr = wid >> 2;      // 0..1 (m half, 128 rows)
    const int wc = wid & 3;       // 0..3 (n quarter, 64 cols)
    const long mBase = (long)blockIdx.y * 256;
    const long nBase = (long)blockIdx.x * 256;

    // staging: thread t owns LDS bytes p0=t*16 (rows 0..127) and p0+8192 (rows 128..255)
    // of each 16KB tile; global source = inverse-swizzled logical element.
    const int p0 = t * 16;
    const int q0 = p0 ^ (((p0 >> 7) & 7) << 4);
    const int sm = q0 >> 6;
    const int sk = (q0 & 63) >> 1;
    const bf16_t* gA = A + (mBase + sm) * (long)REP + sk;
    const bf16_t* gB = B + (nBase + sm) * (long)REP + sk;
    const int dOff = wid * 1024;

#define STAGE_A(kt) do { const int _k = (kt); const bf16_t* _s = gA + _k * 32; \
        char* _d = (char*)As[_k & 3] + dOff; \
        gload_lds16(_s, _d); \
        gload_lds16(_s + 128 * (long)REP, _d + 8192); } while (0)
#define STAGE_B(kt) do { const int _k = (kt); const bf16_t* _s = gB + _k * 32; \
        char* _d = (char*)Bs[_k & 3] + dOff; \
        gload_lds16(_s, _d); \
        gload_lds16(_s + 128 * (long)REP, _d + 8192); } while (0)

    // ds_read bases (swizzled); frag-to-frag offset is a constant 1024B (mi*16 rows
    // don't touch the swizzle key bits (row>>1)&7 only sees row bits 1..3).
    const int rA = wr * 128 + lr;
    const unsigned apA = (unsigned)((rA * 64 + lq * 16) ^ (((rA >> 1) & 7) << 4));
    const int rB = wc * 64 + lr;
    const unsigned apB = (unsigned)((rB * 64 + lq * 16) ^ (((rB >> 1) & 7) << 4));
    const unsigned baseA = ldsAddr(&As[0][0]) + apA;
    const unsigned baseB = ldsAddr(&Bs[0][0]) + apB;

    f32x4 acc[8][4] = {};

    // prologue: tiles 0,1,2 in flight (12 gloads); drain tile 0 (keep 8 outstanding)
    STAGE_A(0); STAGE_B(0);
    STAGE_A(1); STAGE_B(1);
    STAGE_A(2); STAGE_B(2);
    asm volatile("s_waitcnt vmcnt(8)" ::: "memory");
    BAR();

#pragma unroll 4
    for (int k = 0; k < KT; ++k) {
        const int pre = (k + 3 < KT) ? k + 3 : KT - 1;   // idempotent tail re-stage
        const unsigned aA = baseA + (unsigned)((k & 3) * 16384);
        const unsigned aB = baseB + (unsigned)((k & 3) * 16384);

        // ---- phase 0: read A0-3 + B0-3, stage A(pre), MFMA m0-3 x n0-3 ----
        bf16x8 a[4], b[4];
        a[0] = ds_read_b128_off<0>(aA);
        a[1] = ds_read_b128_off<1024>(aA);
        a[2] = ds_read_b128_off<2048>(aA);
        a[3] = ds_read_b128_off<3072>(aA);
        b[0] = ds_read_b128_off<0>(aB);
        b[1] = ds_read_b128_off<1024>(aB);
        b[2] = ds_read_b128_off<2048>(aB);
        b[3] = ds_read_b128_off<3072>(aB);
        STAGE_A(pre);
        BAR();
        asm volatile("s_waitcnt lgkmcnt(0)" ::: "memory");
        __builtin_amdgcn_sched_barrier(0);
        __builtin_amdgcn_s_setprio(1);
#pragma unroll
        for (int mi = 0; mi < 4; ++mi)
#pragma unroll
            for (int ni = 0; ni < 4; ++ni)
                acc[mi][ni] = __builtin_amdgcn_mfma_f32_16x16x32_bf16(a[mi], b[ni], acc[mi][ni], 0, 0, 0);
        __builtin_amdgcn_s_setprio(0);
        __builtin_amdgcn_sched_barrier(0);
        BAR();

        // ---- phase 1: read A4-7 (reuse b), stage B(pre), MFMA m4-7 x n0-3 ----
        bf16x8 c[4];
        c[0] = ds_read_b128_off<4096>(aA);
        c[1] = ds_read_b128_off<5120>(aA);
        c[2] = ds_read_b128_off<6144>(aA);
        c[3] = ds_read_b128_off<7168>(aA);
        STAGE_B(pre);
        BAR();
        asm volatile("s_waitcnt lgkmcnt(0)" ::: "memory");
        __builtin_amdgcn_sched_barrier(0);
        __builtin_amdgcn_s_setprio(1);
#pragma unroll
        for (int mi = 0; mi < 4; ++mi)
#pragma unroll
            for (int ni = 0; ni < 4; ++ni)
                acc[mi + 4][ni] = __builtin_amdgcn_mfma_f32_16x16x32_bf16(c[mi], b[ni], acc[mi + 4][ni], 0, 0, 0);
        __builtin_amdgcn_s_setprio(0);
        __builtin_amdgcn_sched_barrier(0);
        asm volatile("s_waitcnt vmcnt(8)" ::: "memory");  // tile k+1 fully resident
        BAR();
    }
#undef STAGE_A
#undef STAGE_B

    // epilogue: C/D layout (m89): row=(l>>4)*4+j, col=l&15 within 16x16
    float wreg[4];
#pragma unroll
    for (int ni = 0; ni < 4; ++ni) wreg[ni] = wcol[nBase + wc * 64 + ni * 16 + lr];

#pragma unroll
    for (int mi = 0; mi < 8; ++mi)
#pragma unroll
        for (int j = 0; j < 4; ++j) {
            float s = 0.f;
#pragma unroll
            for (int ni = 0; ni < 4; ++ni) {
                const float av = acc[mi][ni][j];
                s += av * fabsf(av) * wreg[ni];
            }
            s += __shfl_xor(s, 1);
            s += __shfl_xor(s, 2);
            s += __shfl_xor(s, 4);
            s += __shfl_xor(s, 8);
            if (lr == 0) red[wc][wr * 128 + mi * 16 + lq * 4 + j] = s;
        }
    __syncthreads();
    if (t < 256)
        partial[(long)blockIdx.x * N_Q + mBase + t]
            = red[0][t] + red[1][t] + red[2][t] + red[3][t];
}

// ---------------- final: out[i] = sum_nb partial[nb][i] + We_b ----------------
__global__ void final_reduce(const float* __restrict__ partial, const float* __restrict__ We_b,
                             float* __restrict__ out) {
    int i = blockIdx.x * blockDim.x + threadIdx.x;
    if (i < N_Q) {
        float s = 0.f;
        for (int nb = 0; nb < N_D / 256; ++nb) s += partial[(long)nb * N_Q + i];
        out[i] = s + We_b[0];
    }
}

extern "C" void kernel_launch(void* const* d_in, const int* in_sizes, int n_in,
                              void* d_out, int out_size, void* d_ws, size_t ws_size,
                              hipStream_t stream) {
    const float* X    = (const float*)d_in[0];
    const float* D    = (const float*)d_in[1];
    const float* R    = (const float*)d_in[2];
    const float* Wx_w = (const float*)d_in[3];
    const float* Wx_b = (const float*)d_in[4];
    const float* Wd_w = (const float*)d_in[5];
    const float* Wd_b = (const float*)d_in[6];
    const float* We_w = (const float*)d_in[7];
    const float* We_b = (const float*)d_in[8];
    const float* enc  = (const float*)d_in[9];
    const float* pos  = (const float*)d_in[10];
    float* out = (float*)d_out;

    char* ws = (char*)d_ws;
    bf16_t* Xb   = (bf16_t*)ws; ws += (size_t)N_Q * D_IN * 2;
    bf16_t* Db   = (bf16_t*)ws; ws += (size_t)N_D * D_IN * 2;
    bf16_t* Wxb  = (bf16_t*)ws; ws += (size_t)REP * D_IN * 2;
    bf16_t* Wdb  = (bf16_t*)ws; ws += (size_t)REP * D_IN * 2;
    bf16_t* Xw   = (bf16_t*)ws; ws += (size_t)N_Q * REP * 2;
    bf16_t* Dw   = (bf16_t*)ws; ws += (size_t)N_D * REP * 2;
    float*  wvec = (float*)ws;  ws += (size_t)N_D * 4;
    float*  part = (float*)ws;  ws += (size_t)(N_D / 256) * N_Q * 4;

    constexpr int PREP_N = (N_Q * D_IN + N_D * D_IN + 2 * REP * D_IN) / 4 + N_D;
    prep<<<(PREP_N + 255) / 256, 256, 0, stream>>>(
        X, D, Wx_w, Wd_w, Xb, Db, Wxb, Wdb, R, enc, pos, We_w, wvec);

    proj_gemm<<<dim3(REP / 128, (N_Q + N_D) / 128), 256, 0, stream>>>(
        Xb, Db, Wxb, Wdb, Wx_b, Wd_b, Xw, Dw);

    gemm_fused256<<<dim3(N_D / 256, N_Q / 256), 512, 0, stream>>>(Xw, Dw, wvec, part);

    final_reduce<<<(N_Q + 255) / 256, 256, 0, stream>>>(part, We_b, out);
}

// Round 5
// 102.189 us; speedup vs baseline: 1.4840x; 1.0513x over previous
//
#include <hip/hip_runtime.h>
#include <hip/hip_bf16.h>

#define N_Q 4096
#define N_D 8192
#define D_IN 768
#define REP 768
#define NENC 129
#define RDIM 4
#define KT 24   // 768/32 K-tiles

typedef __bf16 bf16_t;
typedef __bf16 bf16x4 __attribute__((ext_vector_type(4)));
typedef __bf16 bf16x8 __attribute__((ext_vector_type(8)));
typedef float f32x4 __attribute__((ext_vector_type(4)));

__device__ __forceinline__ void gload_lds16(const void* g, void* l) {
    __builtin_amdgcn_global_load_lds(
        (const __attribute__((address_space(1))) void*)g,
        (__attribute__((address_space(3))) void*)l,
        16, 0, 0);
}

__device__ __forceinline__ unsigned ldsAddr(const void* p) {
    return (unsigned)(unsigned long long)(const __attribute__((address_space(3))) char*)p;
}

template <int OFF>
__device__ __forceinline__ bf16x8 ds_read_b128_off(unsigned addr) {
    bf16x8 r;
    asm volatile("ds_read_b128 %0, %1 offset:%2" : "=v"(r) : "v"(addr), "i"(OFF));
    return r;
}

#define BAR() asm volatile("s_barrier" ::: "memory")

// ---------------- prep: all f32->bf16 casts + per-doc weight, ONE launch ----------------
__device__ __forceinline__ void cast4(const float* __restrict__ s, bf16_t* __restrict__ d, int i) {
    const float4 v = reinterpret_cast<const float4*>(s)[i];
    bf16x4 o;
    o[0] = (bf16_t)v.x; o[1] = (bf16_t)v.y; o[2] = (bf16_t)v.z; o[3] = (bf16_t)v.w;
    reinterpret_cast<bf16x4*>(d)[i] = o;
}

__global__ void prep(const float* __restrict__ X, const float* __restrict__ D,
                     const float* __restrict__ Wx, const float* __restrict__ Wd,
                     bf16_t* __restrict__ Xb, bf16_t* __restrict__ Db,
                     bf16_t* __restrict__ Wxb, bf16_t* __restrict__ Wdb,
                     const float* __restrict__ R, const float* __restrict__ enc,
                     const float* __restrict__ pos, const float* __restrict__ We_w,
                     float* __restrict__ wout) {
    constexpr int C_X  = N_Q * D_IN / 4;
    constexpr int C_D  = C_X + N_D * D_IN / 4;
    constexpr int C_WX = C_D + REP * D_IN / 4;
    constexpr int C_WD = C_WX + REP * D_IN / 4;
    const int i = blockIdx.x * blockDim.x + threadIdx.x;
    if (i < C_X)       cast4(X,  Xb,  i);
    else if (i < C_D)  cast4(D,  Db,  i - C_X);
    else if (i < C_WX) cast4(Wx, Wxb, i - C_D);
    else if (i < C_WD) cast4(Wd, Wdb, i - C_WX);
    else {
        const int j = i - C_WD;
        if (j < N_D) {
            const float r = R[j];
            int best = 0;
            float bd = fabsf(r - enc[0]);
            for (int e = 1; e < NENC; ++e) {
                const float d = fabsf(r - enc[e]);
                if (d < bd) { bd = d; best = e; }   // strict <, matches jnp.argmin
            }
            float s = 0.f;
            for (int d = 0; d < RDIM; ++d) s += pos[best * RDIM + d] * We_w[d];
            wout[j] = s;
        }
    }
}

// ---------------- shared pipelined 256x256 BT-GEMM core ----------------
// 8 waves (2M x 4N), per-wave 128x64 of 16x16x32 frags, BK=32, ring of 4 LDS tiles.
// Intra-wave software pipeline, ONE barrier + ONE vmcnt(4) per K-tile:
//   iter k: issue Q(k)=A-frags m4-7 of tile k; STAGE_A(k+3); lgkmcnt(4) [P(k) done];
//           MFMA phase0; issue P(k+1)=A m0-3 + B n0-3 of tile k+1; STAGE_B(k+3);
//           lgkmcnt(8) [Q(k) done]; MFMA phase1; vmcnt(4) [tile k+2 resident]; BAR.
// Hazards: reads touch bufs {k,k+1}, writes buf {k+3 == k-1 mod 4}; drift <= 1 iter. Disjoint.
// LDS tile layout: q = row*64 + kk*2, p = q ^ (((q>>7)&7)<<4)  (0-conflict, verified r2/r4).
__device__ __forceinline__ void gemm_core(const bf16_t* __restrict__ gA,
                                          const bf16_t* __restrict__ gB,
                                          bf16_t (*As)[8192], bf16_t (*Bs)[8192],
                                          int dOff, unsigned baseA, unsigned baseB,
                                          f32x4 (&acc)[8][4]) {
#define STAGE_A(kt) do { const int _k = (kt); const bf16_t* _s = gA + _k * 32; \
        char* _d = (char*)(As[_k & 3]) + dOff; \
        gload_lds16(_s, _d); \
        gload_lds16(_s + 128 * 768, _d + 8192); } while (0)
#define STAGE_B(kt) do { const int _k = (kt); const bf16_t* _s = gB + _k * 32; \
        char* _d = (char*)(Bs[_k & 3]) + dOff; \
        gload_lds16(_s, _d); \
        gload_lds16(_s + 128 * 768, _d + 8192); } while (0)

    bf16x8 a[4], b[4];

    STAGE_A(0); STAGE_B(0);
    STAGE_A(1); STAGE_B(1);
    STAGE_A(2); STAGE_B(2);
    asm volatile("s_waitcnt vmcnt(4)" ::: "memory");   // tiles 0,1 resident
    BAR();
    // P(0): phase-0 operands of tile 0
    a[0] = ds_read_b128_off<0>(baseA);
    a[1] = ds_read_b128_off<1024>(baseA);
    a[2] = ds_read_b128_off<2048>(baseA);
    a[3] = ds_read_b128_off<3072>(baseA);
    b[0] = ds_read_b128_off<0>(baseB);
    b[1] = ds_read_b128_off<1024>(baseB);
    b[2] = ds_read_b128_off<2048>(baseB);
    b[3] = ds_read_b128_off<3072>(baseB);

#pragma unroll 4
    for (int k = 0; k < KT; ++k) {
        const int pre = (k + 3 < KT) ? k + 3 : KT - 1;   // idempotent tail re-stage
        const unsigned aA = baseA + (unsigned)((k & 3) * 16384);
        const unsigned nA = baseA + (unsigned)(((k + 1) & 3) * 16384);
        const unsigned nB = baseB + (unsigned)(((k + 1) & 3) * 16384);

        // Q(k): phase-1 A-frags (overlap phase-0 MFMA)
        bf16x8 c[4];
        c[0] = ds_read_b128_off<4096>(aA);
        c[1] = ds_read_b128_off<5120>(aA);
        c[2] = ds_read_b128_off<6144>(aA);
        c[3] = ds_read_b128_off<7168>(aA);
        STAGE_A(pre);
        asm volatile("s_waitcnt lgkmcnt(4)" ::: "memory");  // P(k) retired (DS is FIFO)
        __builtin_amdgcn_sched_barrier(0);
        __builtin_amdgcn_s_setprio(1);
#pragma unroll
        for (int mi = 0; mi < 4; ++mi)
#pragma unroll
            for (int ni = 0; ni < 4; ++ni)
                acc[mi][ni] = __builtin_amdgcn_mfma_f32_16x16x32_bf16(a[mi], b[ni], acc[mi][ni], 0, 0, 0);
        __builtin_amdgcn_s_setprio(0);

        // P(k+1): next tile phase-0 operands (overlap phase-1 MFMA); unconditional
        // (last iter reads stale buf into dead regs -> keeps lgkmcnt counts uniform)
        bf16x8 an[4], bn[4];
        an[0] = ds_read_b128_off<0>(nA);
        an[1] = ds_read_b128_off<1024>(nA);
        an[2] = ds_read_b128_off<2048>(nA);
        an[3] = ds_read_b128_off<3072>(nA);
        bn[0] = ds_read_b128_off<0>(nB);
        bn[1] = ds_read_b128_off<1024>(nB);
        bn[2] = ds_read_b128_off<2048>(nB);
        bn[3] = ds_read_b128_off<3072>(nB);
        STAGE_B(pre);
        asm volatile("s_waitcnt lgkmcnt(8)" ::: "memory");  // Q(k) retired
        __builtin_amdgcn_sched_barrier(0);
        __builtin_amdgcn_s_setprio(1);
#pragma unroll
        for (int mi = 0; mi < 4; ++mi)
#pragma unroll
            for (int ni = 0; ni < 4; ++ni)
                acc[mi + 4][ni] = __builtin_amdgcn_mfma_f32_16x16x32_bf16(c[mi], b[ni], acc[mi + 4][ni], 0, 0, 0);
        __builtin_amdgcn_s_setprio(0);
        asm volatile("s_waitcnt vmcnt(4)" ::: "memory");    // tile k+2 fully resident
        BAR();
#pragma unroll
        for (int i = 0; i < 4; ++i) { a[i] = an[i]; b[i] = bn[i]; }
    }
#undef STAGE_A
#undef STAGE_B
}

// ---------------- merged projection GEMM on the pipelined core ----------------
__global__ __launch_bounds__(512)
void proj_pipe(const bf16_t* __restrict__ Xb, const bf16_t* __restrict__ Db,
               const bf16_t* __restrict__ Wxb, const bf16_t* __restrict__ Wdb,
               const float* __restrict__ bx, const float* __restrict__ bd,
               bf16_t* __restrict__ Xw, bf16_t* __restrict__ Dw) {
    __shared__ bf16_t As[4][8192];
    __shared__ bf16_t Bs[4][8192];

    const bool isX = blockIdx.y < (N_Q / 256);
    const bf16_t* A  = isX ? Xb : Db;
    const bf16_t* Bw = isX ? Wxb : Wdb;
    const float* bias = isX ? bx : bd;
    bf16_t* C = isX ? Xw : Dw;
    const long mBase = (long)(isX ? blockIdx.y : blockIdx.y - N_Q / 256) * 256;
    const long nBase = (long)blockIdx.x * 256;

    const int t = threadIdx.x;
    const int lane = t & 63;
    const int wid = t >> 6;
    const int lr = lane & 15;
    const int lq = lane >> 4;
    const int wr = wid >> 2;
    const int wc = wid & 3;

    const int p0 = t * 16;
    const int q0 = p0 ^ (((p0 >> 7) & 7) << 4);
    const int sm = q0 >> 6;
    const int sk = (q0 & 63) >> 1;
    const bf16_t* gA = A  + (mBase + sm) * (long)REP + sk;
    const bf16_t* gB = Bw + (nBase + sm) * (long)REP + sk;
    const int dOff = wid * 1024;

    const int rA = wr * 128 + lr;
    const unsigned apA = (unsigned)((rA * 64 + lq * 16) ^ (((rA >> 1) & 7) << 4));
    const int rB = wc * 64 + lr;
    const unsigned apB = (unsigned)((rB * 64 + lq * 16) ^ (((rB >> 1) & 7) << 4));
    const unsigned baseA = ldsAddr(&As[0][0]) + apA;
    const unsigned baseB = ldsAddr(&Bs[0][0]) + apB;

    f32x4 acc[8][4] = {};
    gemm_core(gA, gB, As, Bs, dOff, baseA, baseB, acc);

    // epilogue: bias + bf16 store. D layout: row=(l>>4)*4+j, col=l&15 per 16x16
#pragma unroll
    for (int ni = 0; ni < 4; ++ni) {
        const int col = (int)nBase + wc * 64 + ni * 16 + lr;
        const float bv = bias[col];
#pragma unroll
        for (int mi = 0; mi < 8; ++mi)
#pragma unroll
            for (int j = 0; j < 4; ++j) {
                const long row = mBase + wr * 128 + mi * 16 + lq * 4 + j;
                C[row * (long)REP + col] = (bf16_t)(acc[mi][ni][j] + bv);
            }
    }
}

// ---------------- fused similarity GEMM + power-sign + weighted row-reduce ----------------
__global__ __launch_bounds__(512)
void fused_pipe(const bf16_t* __restrict__ A, const bf16_t* __restrict__ B,
                const float* __restrict__ wcol, float* __restrict__ partial) {
    __shared__ bf16_t As[4][8192];
    __shared__ bf16_t Bs[4][8192];
    __shared__ float red[4][256];

    const int t = threadIdx.x;
    const int lane = t & 63;
    const int wid = t >> 6;
    const int lr = lane & 15;
    const int lq = lane >> 4;
    const int wr = wid >> 2;
    const int wc = wid & 3;
    const long mBase = (long)blockIdx.y * 256;
    const long nBase = (long)blockIdx.x * 256;

    const int p0 = t * 16;
    const int q0 = p0 ^ (((p0 >> 7) & 7) << 4);
    const int sm = q0 >> 6;
    const int sk = (q0 & 63) >> 1;
    const bf16_t* gA = A + (mBase + sm) * (long)REP + sk;
    const bf16_t* gB = B + (nBase + sm) * (long)REP + sk;
    const int dOff = wid * 1024;

    const int rA = wr * 128 + lr;
    const unsigned apA = (unsigned)((rA * 64 + lq * 16) ^ (((rA >> 1) & 7) << 4));
    const int rB = wc * 64 + lr;
    const unsigned apB = (unsigned)((rB * 64 + lq * 16) ^ (((rB >> 1) & 7) << 4));
    const unsigned baseA = ldsAddr(&As[0][0]) + apA;
    const unsigned baseB = ldsAddr(&Bs[0][0]) + apB;

    f32x4 acc[8][4] = {};
    gemm_core(gA, gB, As, Bs, dOff, baseA, baseB, acc);

    // epilogue: f(a)*w, reduce over n cols
    float wreg[4];
#pragma unroll
    for (int ni = 0; ni < 4; ++ni) wreg[ni] = wcol[nBase + wc * 64 + ni * 16 + lr];

#pragma unroll
    for (int mi = 0; mi < 8; ++mi)
#pragma unroll
        for (int j = 0; j < 4; ++j) {
            float s = 0.f;
#pragma unroll
            for (int ni = 0; ni < 4; ++ni) {
                const float av = acc[mi][ni][j];
                s += av * fabsf(av) * wreg[ni];
            }
            s += __shfl_xor(s, 1);
            s += __shfl_xor(s, 2);
            s += __shfl_xor(s, 4);
            s += __shfl_xor(s, 8);
            if (lr == 0) red[wc][wr * 128 + mi * 16 + lq * 4 + j] = s;
        }
    __syncthreads();
    if (t < 256)
        partial[(long)blockIdx.x * N_Q + mBase + t]
            = red[0][t] + red[1][t] + red[2][t] + red[3][t];
}

// ---------------- final: out[i] = sum_nb partial[nb][i] + We_b ----------------
__global__ void final_reduce(const float* __restrict__ partial, const float* __restrict__ We_b,
                             float* __restrict__ out) {
    int i = blockIdx.x * blockDim.x + threadIdx.x;
    if (i < N_Q) {
        float s = 0.f;
        for (int nb = 0; nb < N_D / 256; ++nb) s += partial[(long)nb * N_Q + i];
        out[i] = s + We_b[0];
    }
}

extern "C" void kernel_launch(void* const* d_in, const int* in_sizes, int n_in,
                              void* d_out, int out_size, void* d_ws, size_t ws_size,
                              hipStream_t stream) {
    const float* X    = (const float*)d_in[0];
    const float* D    = (const float*)d_in[1];
    const float* R    = (const float*)d_in[2];
    const float* Wx_w = (const float*)d_in[3];
    const float* Wx_b = (const float*)d_in[4];
    const float* Wd_w = (const float*)d_in[5];
    const float* Wd_b = (const float*)d_in[6];
    const float* We_w = (const float*)d_in[7];
    const float* We_b = (const float*)d_in[8];
    const float* enc  = (const float*)d_in[9];
    const float* pos  = (const float*)d_in[10];
    float* out = (float*)d_out;

    char* ws = (char*)d_ws;
    bf16_t* Xb   = (bf16_t*)ws; ws += (size_t)N_Q * D_IN * 2;
    bf16_t* Db   = (bf16_t*)ws; ws += (size_t)N_D * D_IN * 2;
    bf16_t* Wxb  = (bf16_t*)ws; ws += (size_t)REP * D_IN * 2;
    bf16_t* Wdb  = (bf16_t*)ws; ws += (size_t)REP * D_IN * 2;
    bf16_t* Xw   = (bf16_t*)ws; ws += (size_t)N_Q * REP * 2;
    bf16_t* Dw   = (bf16_t*)ws; ws += (size_t)N_D * REP * 2;
    float*  wvec = (float*)ws;  ws += (size_t)N_D * 4;
    float*  part = (float*)ws;  ws += (size_t)(N_D / 256) * N_Q * 4;

    constexpr int PREP_N = (N_Q * D_IN + N_D * D_IN + 2 * REP * D_IN) / 4 + N_D;
    prep<<<(PREP_N + 255) / 256, 256, 0, stream>>>(
        X, D, Wx_w, Wd_w, Xb, Db, Wxb, Wdb, R, enc, pos, We_w, wvec);

    proj_pipe<<<dim3(REP / 256, (N_Q + N_D) / 256), 512, 0, stream>>>(
        Xb, Db, Wxb, Wdb, Wx_b, Wd_b, Xw, Dw);

    fused_pipe<<<dim3(N_D / 256, N_Q / 256), 512, 0, stream>>>(Xw, Dw, wvec, part);

    final_reduce<<<(N_Q + 255) / 256, 256, 0, stream>>>(part, We_b, out);
}